// Round 3
// baseline (240.017 us; speedup 1.0000x reference)
//
#include <hip/hip_runtime.h>
#include <hip/hip_bf16.h>
#include <math.h>

#define DIMC 384
#define NH 6
#define HD 64
#define MLPD 1536
#define BS 8
#define SEQ 1024
#define T_TOK (BS*SEQ)                  // 8192 tokens
#define TC ((size_t)T_TOK*DIMC)         // 3,145,728 elems
#define QK_SCALE 0.125f                 // 64^-0.5

typedef __bf16 bf16;
typedef bf16 bf16x4 __attribute__((ext_vector_type(4)));
typedef bf16 bf16x8 __attribute__((ext_vector_type(8)));
typedef float floatx4 __attribute__((ext_vector_type(4)));

// async global->LDS 16B (per-lane LDS dest must equal wave-uniform-base + lane*16)
__device__ __forceinline__ void async_cp16(const void* gsrc, void* ldst) {
    __builtin_amdgcn_global_load_lds(
        (const __attribute__((address_space(1))) unsigned int*)gsrc,
        (__attribute__((address_space(3))) unsigned int*)ldst,
        16, 0, 0);
}

// ---------- fp32 -> bf16 weight conversion (qkv_w | proj_w | w1 | w2 contiguous) ----------
__global__ __launch_bounds__(256)
void cvt_all(const float* __restrict__ s0, const float* __restrict__ s1,
             const float* __restrict__ s2, const float* __restrict__ s3,
             bf16* __restrict__ dst) {
    int i = blockIdx.x * 256 + threadIdx.x;   // i < 442368 float4 chunks
    const int n0 = 110592, n1 = 36864, n2 = 147456;   // float4 counts
    const float4* src; int j;
    if (i < n0)           { src = (const float4*)s0; j = i; }
    else if (i < n0+n1)   { src = (const float4*)s1; j = i - n0; }
    else if (i < n0+n1+n2){ src = (const float4*)s2; j = i - n0 - n1; }
    else                  { src = (const float4*)s3; j = i - n0 - n1 - n2; }
    float4 v = src[j];
    bf16x4 o; o[0] = (bf16)v.x; o[1] = (bf16)v.y; o[2] = (bf16)v.z; o[3] = (bf16)v.w;
    ((bf16x4*)dst)[i] = o;
}

// ---------------- LayerNorm: 256 thr = 4 rows (1 wave/row), fp32 in, bf16 out ----------
__global__ __launch_bounds__(256)
void ln_kernel(const float* __restrict__ x, const float* __restrict__ w,
               const float* __restrict__ b, bf16* __restrict__ out) {
    int row = blockIdx.x * 4 + (threadIdx.x >> 6);
    int t = threadIdx.x & 63;
    const float* xr = x + (size_t)row * DIMC;
    float vals[6];
    float s = 0.f;
    #pragma unroll
    for (int i = 0; i < 6; i++) { vals[i] = xr[t + i*64]; s += vals[i]; }
    #pragma unroll
    for (int m = 32; m; m >>= 1) s += __shfl_xor(s, m);
    float mean = s * (1.0f / DIMC);
    float sq = 0.f;
    #pragma unroll
    for (int i = 0; i < 6; i++) { float d = vals[i] - mean; sq += d * d; }
    #pragma unroll
    for (int m = 32; m; m >>= 1) sq += __shfl_xor(sq, m);
    float rstd = rsqrtf(sq * (1.0f / DIMC) + 1e-5f);
    bf16* orow = out + (size_t)row * DIMC;
    #pragma unroll
    for (int i = 0; i < 6; i++) {
        int c = t + i*64;
        orow[c] = (bf16)((vals[i] - mean) * rstd * w[c] + b[c]);
    }
}

// ---- fused: x1 = x + Pp0 + Pp1 + proj_b (write fp32 x1) ; h = LN2(x1) (write bf16) ----
__global__ __launch_bounds__(256)
void ln2_fused(const float* __restrict__ x, const bf16* __restrict__ p0,
               const bf16* __restrict__ p1, const float* __restrict__ pb,
               const float* __restrict__ w, const float* __restrict__ b,
               float* __restrict__ x1, bf16* __restrict__ h) {
    int row = blockIdx.x * 4 + (threadIdx.x >> 6);
    int t = threadIdx.x & 63;
    size_t base = (size_t)row * DIMC;
    float vals[6];
    float s = 0.f;
    #pragma unroll
    for (int i = 0; i < 6; i++) {
        int c = t + i*64;
        float v = x[base + c] + (float)p0[base + c] + (float)p1[base + c] + pb[c];
        vals[i] = v; s += v;
    }
    #pragma unroll
    for (int m = 32; m; m >>= 1) s += __shfl_xor(s, m);
    float mean = s * (1.0f / DIMC);
    float sq = 0.f;
    #pragma unroll
    for (int i = 0; i < 6; i++) { float d = vals[i] - mean; sq += d * d; }
    #pragma unroll
    for (int m = 32; m; m >>= 1) sq += __shfl_xor(sq, m);
    float rstd = rsqrtf(sq * (1.0f / DIMC) + 1e-5f);
    #pragma unroll
    for (int i = 0; i < 6; i++) {
        int c = t + i*64;
        x1[base + c] = vals[i];
        h[base + c] = (bf16)((vals[i] - mean) * rstd * w[c] + b[c]);
    }
}

// ---- final: out = x1 + b2 + Pm0+Pm1+Pm2+Pm3 (bf16 partials), float4-vectorized ----
__global__ __launch_bounds__(256)
void reduce4(float* __restrict__ xo, const bf16* __restrict__ p0, const bf16* __restrict__ p1,
             const bf16* __restrict__ p2, const bf16* __restrict__ p3,
             const float* __restrict__ b2) {
    int i = blockIdx.x * 256 + threadIdx.x;   // float4 index, < TC/4
    float4 v = ((const float4*)xo)[i];
    int c = (i % 96) * 4;
    float4 bb = *(const float4*)(b2 + c);
    bf16x4 a0 = ((const bf16x4*)p0)[i], a1 = ((const bf16x4*)p1)[i];
    bf16x4 a2 = ((const bf16x4*)p2)[i], a3 = ((const bf16x4*)p3)[i];
    v.x += bb.x + (float)a0[0] + (float)a1[0] + (float)a2[0] + (float)a3[0];
    v.y += bb.y + (float)a0[1] + (float)a1[1] + (float)a2[1] + (float)a3[1];
    v.z += bb.z + (float)a0[2] + (float)a1[2] + (float)a2[2] + (float)a3[2];
    v.w += bb.w + (float)a0[3] + (float)a1[3] + (float)a2[3] + (float)a3[3];
    ((float4*)xo)[i] = v;
}

// ---------------- GEMM: C[M,N] = A[M,K] @ W[N,K]^T, m97-style LDS staging ----------------
enum { EPI_NONE = 0, EPI_QKV = 1, EPI_GELU = 3 };

template<int EPI, int K, int KS, typename OutT>
__global__ __launch_bounds__(256)
void gemm_bt(const bf16* __restrict__ A, const bf16* __restrict__ W,
             const float* __restrict__ bias, OutT* out, int M, int N) {
    __shared__ __align__(16) bf16 Ash[128*32];
    __shared__ __align__(16) bf16 Bsh[128*32];
    constexpr int KB = K / KS;               // K extent per block
    int tid = threadIdx.x;
    int lane = tid & 63, w = tid >> 6;
    int quad = lane >> 4, l16 = lane & 15;
    int rbase = blockIdx.y * 128 + (w >> 1) * 64;
    int cbase = blockIdx.x * 128 + (w & 1) * 64;
    int kbase = blockIdx.z * KB;
    int c1 = w * 64 + lane;                  // [0,256)
    int c2 = c1 + 256;                       // [256,512)
    const bf16* Ag1 = A + (size_t)(blockIdx.y*128 + (c1 >> 2)) * K + kbase + (c1 & 3) * 8;
    const bf16* Ag2 = A + (size_t)(blockIdx.y*128 + (c2 >> 2)) * K + kbase + (c2 & 3) * 8;
    const bf16* Wg1 = W + (size_t)(blockIdx.x*128 + (c1 >> 2)) * K + kbase + (c1 & 3) * 8;
    const bf16* Wg2 = W + (size_t)(blockIdx.x*128 + (c2 >> 2)) * K + kbase + (c2 & 3) * 8;
    bf16* As1 = Ash + c1 * 8;  bf16* As2 = Ash + c2 * 8;
    bf16* Bs1 = Bsh + c1 * 8;  bf16* Bs2 = Bsh + c2 * 8;

    int arow = (w >> 1) * 64;                // wave's row offset within tile
    int brow = (w & 1) * 64;
    floatx4 acc[4][4] = {};
    #pragma unroll
    for (int kk = 0; kk < KB / 32; kk++) {
        __syncthreads();                     // prev iter's LDS reads complete
        async_cp16(Ag1 + kk*32, As1);
        async_cp16(Ag2 + kk*32, As2);
        async_cp16(Wg1 + kk*32, Bs1);
        async_cp16(Wg2 + kk*32, Bs2);
        __syncthreads();                     // drains vmcnt (lds-DMA) + lgkmcnt
        bf16x8 a[4], bfr[4];
        #pragma unroll
        for (int tm = 0; tm < 4; tm++)
            a[tm] = *(const bf16x8*)&Ash[(arow + tm*16 + l16) * 32 + quad*8];
        #pragma unroll
        for (int tn = 0; tn < 4; tn++)
            bfr[tn] = *(const bf16x8*)&Bsh[(brow + tn*16 + l16) * 32 + quad*8];
        #pragma unroll
        for (int tm = 0; tm < 4; tm++)
            #pragma unroll
            for (int tn = 0; tn < 4; tn++)
                acc[tm][tn] = __builtin_amdgcn_mfma_f32_16x16x32_bf16(a[tm], bfr[tn], acc[tm][tn], 0, 0, 0);
    }

    #pragma unroll
    for (int tm = 0; tm < 4; tm++)
        #pragma unroll
        for (int tn = 0; tn < 4; tn++) {
            if constexpr (EPI == EPI_QKV) {
                int colb = cbase + tn*16 + l16;       // uniform 'which' per tile (384%16==0)
                int which = colb / 384;
                int rowb = rbase + tm*16 + quad*4;
                int bb = rowb >> 10;
                if (which == 2) {
                    // V transposed: [B,H,D,N]; 4 consecutive n -> packed 8B store
                    int rem = colb - 768;
                    int hh = rem >> 6, d = rem & 63;
                    int n = rowb & 1023;
                    bf16x4 pk;
                    #pragma unroll
                    for (int r = 0; r < 4; r++) pk[r] = (bf16)acc[tm][tn][r];
                    *(bf16x4*)((bf16*)out + 2*TC + (((size_t)(bb*NH + hh) * HD + d) << 10) + n) = pk;
                } else {
                    int rem = colb - which*384;
                    int hh = rem >> 6, d = rem & 63;
                    #pragma unroll
                    for (int r = 0; r < 4; r++) {
                        int n = (rowb & 1023) + r;
                        ((bf16*)out)[(size_t)which*TC + (((size_t)(bb*NH + hh) * SEQ + n) << 6) + d]
                            = (bf16)acc[tm][tn][r];
                    }
                }
            } else if constexpr (EPI == EPI_NONE) {
                OutT* ob = out + (size_t)blockIdx.z * M * N;
                #pragma unroll
                for (int r = 0; r < 4; r++) {
                    int row = rbase + tm*16 + quad*4 + r;
                    int col = cbase + tn*16 + l16;
                    ob[(size_t)row * N + col] = (OutT)acc[tm][tn][r];
                }
            } else {  // EPI_GELU
                #pragma unroll
                for (int r = 0; r < 4; r++) {
                    int row = rbase + tm*16 + quad*4 + r;
                    int col = cbase + tn*16 + l16;
                    float v = acc[tm][tn][r] + bias[col];
                    v = 0.5f * v * (1.0f + erff(v * 0.70710678118f));
                    out[(size_t)row * N + col] = (OutT)v;
                }
            }
        }
}

// ---------------- Fused L2Q attention, split-K across 4 waves ----------------
// Round-3 changes (occupancy supply fix — grid was the binding constraint):
//  (1) q-tile 64 -> 32 rows: grid 768 -> 1536 blocks (6/CU), per-wave state halved.
//  (2) __launch_bounds__(256,4): VGPR<=128 (132 was over the 128 occupancy step ->
//      8 waves/CU cap; now 16 waves/CU).
//  (3) Register prefetch without double-buffer: kf(t+1) issued into the same regs
//      right after QK^T(t) consumes them; vf(t) issued before P-write, consumed by PV.
//  (4) LDS 18432 B (4x[32][72] P-tiles + [64][68] fp32 reduction overlay).
__global__ __launch_bounds__(256, 4)
void attn_kernel(const bf16* __restrict__ q, const bf16* __restrict__ k,
                 const bf16* __restrict__ vt, const float* __restrict__ alpha,
                 const float* __restrict__ beta, const float* __restrict__ gamma,
                 bf16* __restrict__ attn_out) {
    __shared__ __align__(16) char smem[18432];
    bf16  (*Psh)[72] = (bf16(*)[72])smem;       // [4*32][72] wave-private P tiles
    float (*RedA)[68] = (float(*)[68])smem;     // [32][68] (col 64 = rowsum)
    float (*RedB)[68] = RedA + 32;              // [32][68]

    int L = blockIdx.x;
    int xcd = L & 7, slot = L >> 3;             // slot in [0,192)
    int qt = slot & 31;                         // 32 q-tiles of 32 rows
    int bh = xcd + ((slot >> 5) << 3);          // {xcd, xcd+8, ..., xcd+40}
    int bb = bh / NH, h = bh % NH;
    int q0 = qt * 32;
    int tid = threadIdx.x;
    int w = tid >> 6, lane = tid & 63, quad = lane >> 4, l16 = lane & 15;
    float av = alpha[h] * (QK_SCALE * QK_SCALE), bv = beta[h] * QK_SCALE, gv = gamma[h];
    const bf16* qb  = q  + (size_t)bh * SEQ * HD;
    const bf16* kb  = k  + (size_t)bh * SEQ * HD;
    const bf16* vtb = vt + (size_t)bh * HD * SEQ;

    bf16x8 qa[2][2];
    #pragma unroll
    for (int tm = 0; tm < 2; tm++)
        #pragma unroll
        for (int ks = 0; ks < 2; ks++)
            qa[tm][ks] = *(const bf16x8*)(qb + (size_t)(q0 + tm*16 + l16) * HD + ks*32 + quad*8);

    bf16x8 vone;
    #pragma unroll
    for (int j = 0; j < 8; j++) vone[j] = (bf16)1.0f;

    floatx4 o[2][4] = {};
    floatx4 rsacc[2] = {};
    int prow = w * 32;
    int rd_sw = ((l16 >> 2) & 3) << 3;
    int kt_base = w * 4;

    bf16x8 kf[2][4], vf[2][4];
    // prologue: K fragments for tile 0
    #pragma unroll
    for (int ks = 0; ks < 2; ks++)
        #pragma unroll
        for (int tn = 0; tn < 4; tn++)
            kf[ks][tn] = *(const bf16x8*)(kb + (size_t)(kt_base*64 + tn*16 + l16) * HD + ks*32 + quad*8);

    #pragma unroll
    for (int t = 0; t < 4; t++) {
        int kb0 = (kt_base + t) * 64;
        // QK^T on resident kf + quadratic relu + P write (per tm to limit live regs)
        #pragma unroll
        for (int tm = 0; tm < 2; tm++) {
            floatx4 s[4] = {};
            #pragma unroll
            for (int ks = 0; ks < 2; ks++)
                #pragma unroll
                for (int tn = 0; tn < 4; tn++)
                    s[tn] = __builtin_amdgcn_mfma_f32_16x16x32_bf16(qa[tm][ks], kf[ks][tn], s[tn], 0, 0, 0);
            #pragma unroll
            for (int tn = 0; tn < 4; tn++)
                #pragma unroll
                for (int r = 0; r < 4; r++) {
                    float xx = s[tn][r];
                    float p = fmaxf((av*xx + bv)*xx + gv, 0.f);
                    int row = tm*16 + quad*4 + r;
                    int col = (tn*16 + l16) ^ (quad << 3);   // bank swizzle
                    Psh[prow + row][col] = (bf16)p;
                }
        }
        // kf fully consumed -> issue next tile's K loads into the same registers
        // (latency hides under the V loads + P-write drain + PV MFMAs)
        if (t < 3) {
            int nb0 = kb0 + 64;
            #pragma unroll
            for (int ks = 0; ks < 2; ks++)
                #pragma unroll
                for (int tn = 0; tn < 4; tn++)
                    kf[ks][tn] = *(const bf16x8*)(kb + (size_t)(nb0 + tn*16 + l16) * HD + ks*32 + quad*8);
        }
        // this tile's V fragments (consumed by PV just below)
        #pragma unroll
        for (int ks = 0; ks < 2; ks++)
            #pragma unroll
            for (int tn = 0; tn < 4; tn++)
                vf[ks][tn] = *(const bf16x8*)(vtb + (size_t)(tn*16 + l16) * SEQ + kb0 + ks*32 + quad*8);
        // PV + rowsum
        #pragma unroll
        for (int ks = 0; ks < 2; ks++) {
            bf16x8 pf[2];
            #pragma unroll
            for (int tm = 0; tm < 2; tm++)
                pf[tm] = *(const bf16x8*)&Psh[prow + tm*16 + l16][(ks*32 + quad*8) ^ rd_sw];
            #pragma unroll
            for (int tm = 0; tm < 2; tm++)
                rsacc[tm] = __builtin_amdgcn_mfma_f32_16x16x32_bf16(pf[tm], vone, rsacc[tm], 0, 0, 0);
            #pragma unroll
            for (int tm = 0; tm < 2; tm++)
                #pragma unroll
                for (int tn = 0; tn < 4; tn++)
                    o[tm][tn] = __builtin_amdgcn_mfma_f32_16x16x32_bf16(pf[tm], vf[ks][tn], o[tm][tn], 0, 0, 0);
        }
    }

    // ---- butterfly cross-wave reduction (overlay dead P region) ----
    __syncthreads();                       // B1: all P reads done -> safe to overlay
    if (w & 1) {                           // round 1 write: wave1->slotA, wave3->slotB
        float (*R)[68] = (w == 1) ? RedA : RedB;
        #pragma unroll
        for (int tm = 0; tm < 2; tm++) {
            #pragma unroll
            for (int tn = 0; tn < 4; tn++)
                #pragma unroll
                for (int r = 0; r < 4; r++)
                    R[tm*16 + quad*4 + r][tn*16 + l16] = o[tm][tn][r];
            if (l16 == 0)
                #pragma unroll
                for (int r = 0; r < 4; r++)
                    R[tm*16 + quad*4 + r][64] = rsacc[tm][r];
        }
    }
    __syncthreads();                       // B2
    if (!(w & 1)) {                        // round 1 add: wave0+=A, wave2+=B
        float (*R)[68] = (w == 0) ? RedA : RedB;
        #pragma unroll
        for (int tm = 0; tm < 2; tm++) {
            #pragma unroll
            for (int tn = 0; tn < 4; tn++)
                #pragma unroll
                for (int r = 0; r < 4; r++)
                    o[tm][tn][r] += R[tm*16 + quad*4 + r][tn*16 + l16];
            #pragma unroll
            for (int r = 0; r < 4; r++)
                rsacc[tm][r] += R[tm*16 + quad*4 + r][64];
        }
    }
    __syncthreads();                       // B3: round-1 reads done
    // round 2 cross-write into slotA: w2 -> its tm=0 (rows 0..15), w0 -> its tm=1 (rows 16..31)
    if (w == 2) {
        #pragma unroll
        for (int tn = 0; tn < 4; tn++)
            #pragma unroll
            for (int r = 0; r < 4; r++)
                RedA[quad*4 + r][tn*16 + l16] = o[0][tn][r];
        if (l16 == 0)
            #pragma unroll
            for (int r = 0; r < 4; r++)
                RedA[quad*4 + r][64] = rsacc[0][r];
    } else if (w == 0) {
        #pragma unroll
        for (int tn = 0; tn < 4; tn++)
            #pragma unroll
            for (int r = 0; r < 4; r++)
                RedA[16 + quad*4 + r][tn*16 + l16] = o[1][tn][r];
        if (l16 == 0)
            #pragma unroll
            for (int r = 0; r < 4; r++)
                RedA[16 + quad*4 + r][64] = rsacc[1][r];
    }
    __syncthreads();                       // B4
    if (w == 0) {                          // finish + store rows 0..15
        #pragma unroll
        for (int r = 0; r < 4; r++)
            rsacc[0][r] += RedA[quad*4 + r][64];
        #pragma unroll
        for (int tn = 0; tn < 4; tn++)
            #pragma unroll
            for (int r = 0; r < 4; r++) {
                float ov = o[0][tn][r] + RedA[quad*4 + r][tn*16 + l16];
                int n = q0 + quad*4 + r;
                attn_out[((size_t)(bb*SEQ + n)) * DIMC + h*HD + tn*16 + l16] =
                    (bf16)(ov / (rsacc[0][r] + 1e-6f));
            }
    } else if (w == 2) {                   // finish + store rows 16..31
        #pragma unroll
        for (int r = 0; r < 4; r++)
            rsacc[1][r] += RedA[16 + quad*4 + r][64];
        #pragma unroll
        for (int tn = 0; tn < 4; tn++)
            #pragma unroll
            for (int r = 0; r < 4; r++) {
                float ov = o[1][tn][r] + RedA[16 + quad*4 + r][tn*16 + l16];
                int n = q0 + 16 + quad*4 + r;
                attn_out[((size_t)(bb*SEQ + n)) * DIMC + h*HD + tn*16 + l16] =
                    (bf16)(ov / (rsacc[1][r] + 1e-6f));
            }
    }
}

// ---------------- driver ----------------
extern "C" void kernel_launch(void* const* d_in, const int* in_sizes, int n_in,
                              void* d_out, int out_size, void* d_ws, size_t ws_size,
                              hipStream_t stream) {
    const float* x      = (const float*)d_in[0];
    const float* qkv_w  = (const float*)d_in[1];
    const float* proj_w = (const float*)d_in[2];
    const float* proj_b = (const float*)d_in[3];
    const float* alpha  = (const float*)d_in[4];
    const float* beta   = (const float*)d_in[5];
    const float* gamma  = (const float*)d_in[6];
    const float* ln1_w  = (const float*)d_in[7];
    const float* ln1_b  = (const float*)d_in[8];
    const float* ln2_w  = (const float*)d_in[9];
    const float* ln2_b  = (const float*)d_in[10];
    const float* w1     = (const float*)d_in[11];
    const float* b1     = (const float*)d_in[12];
    const float* w2     = (const float*)d_in[13];
    const float* b2     = (const float*)d_in[14];
    float* out = (float*)d_out;           // fp32 output; also doubles as x1 buffer

    // ws layout unchanged (see journal)
    char* base = (char*)d_ws;
    bf16* wq_bf = (bf16*)base;                 // 1152x384
    bf16* wp_bf = wq_bf + 442368;              // 384x384
    bf16* w1_bf = wq_bf + 589824;              // 1536x384
    bf16* w2_bf = wq_bf + 1179648;             // 384x1536
    bf16* h      = (bf16*)(base + 3538944);
    bf16* qkv    = (bf16*)(base + 9830400);
    bf16* attn_o = (bf16*)(base + 28704768);
    bf16* m      = qkv;                        // overlays qkv+attn_o (both dead by mlp1)
    bf16* Pp     = (bf16*)(base + 34996224);   // 2*TC (proj split-K partials)
    bf16* Pm     = (bf16*)(base + 34996224);   // 4*TC (mlp2 split-K partials; Pp dead)

    cvt_all<<<1728, 256, 0, stream>>>(qkv_w, proj_w, w1, w2, wq_bf);
    ln_kernel<<<T_TOK/4, 256, 0, stream>>>(x, ln1_w, ln1_b, h);
    gemm_bt<EPI_QKV, 384, 1, bf16><<<dim3(9, 64, 1), 256, 0, stream>>>(
        h, wq_bf, nullptr, qkv, T_TOK, 1152);
    attn_kernel<<<1536, 256, 0, stream>>>(
        qkv, qkv + TC, qkv + 2*TC, alpha, beta, gamma, attn_o);
    gemm_bt<EPI_NONE, 384, 2, bf16><<<dim3(3, 64, 2), 256, 0, stream>>>(
        attn_o, wp_bf, nullptr, Pp, T_TOK, DIMC);
    ln2_fused<<<T_TOK/4, 256, 0, stream>>>(x, Pp, Pp + TC, proj_b, ln2_w, ln2_b, out, h);
    gemm_bt<EPI_GELU, 384, 1, bf16><<<dim3(12, 64, 1), 256, 0, stream>>>(
        h, w1_bf, b1, m, T_TOK, MLPD);
    gemm_bt<EPI_NONE, 1536, 4, bf16><<<dim3(3, 64, 4), 256, 0, stream>>>(
        m, w2_bf, nullptr, Pm, T_TOK, DIMC);
    reduce4<<<TC/4/256, 256, 0, stream>>>(out, Pm, Pm + TC, Pm + 2*TC, Pm + 3*TC, b2);
}

// Round 4
// 228.523 us; speedup vs baseline: 1.0503x; 1.0503x over previous
//
#include <hip/hip_runtime.h>
#include <hip/hip_bf16.h>
#include <math.h>

#define DIMC 384
#define NH 6
#define HD 64
#define MLPD 1536
#define BS 8
#define SEQ 1024
#define T_TOK (BS*SEQ)                  // 8192 tokens
#define TC ((size_t)T_TOK*DIMC)         // 3,145,728 elems
#define QK_SCALE 0.125f                 // 64^-0.5

typedef __bf16 bf16;
typedef bf16 bf16x4 __attribute__((ext_vector_type(4)));
typedef bf16 bf16x8 __attribute__((ext_vector_type(8)));
typedef float floatx4 __attribute__((ext_vector_type(4)));

// async global->LDS 16B (per-lane LDS dest must equal wave-uniform-base + lane*16)
__device__ __forceinline__ void async_cp16(const void* gsrc, void* ldst) {
    __builtin_amdgcn_global_load_lds(
        (const __attribute__((address_space(1))) unsigned int*)gsrc,
        (__attribute__((address_space(3))) unsigned int*)ldst,
        16, 0, 0);
}

// ---------- fp32 -> bf16 weight conversion (qkv_w | proj_w | w1 | w2 contiguous) ----------
__global__ __launch_bounds__(256)
void cvt_all(const float* __restrict__ s0, const float* __restrict__ s1,
             const float* __restrict__ s2, const float* __restrict__ s3,
             bf16* __restrict__ dst) {
    int i = blockIdx.x * 256 + threadIdx.x;   // i < 442368 float4 chunks
    const int n0 = 110592, n1 = 36864, n2 = 147456;   // float4 counts
    const float4* src; int j;
    if (i < n0)           { src = (const float4*)s0; j = i; }
    else if (i < n0+n1)   { src = (const float4*)s1; j = i - n0; }
    else if (i < n0+n1+n2){ src = (const float4*)s2; j = i - n0 - n1; }
    else                  { src = (const float4*)s3; j = i - n0 - n1 - n2; }
    float4 v = src[j];
    bf16x4 o; o[0] = (bf16)v.x; o[1] = (bf16)v.y; o[2] = (bf16)v.z; o[3] = (bf16)v.w;
    ((bf16x4*)dst)[i] = o;
}

// ---------------- LayerNorm: 256 thr = 4 rows (1 wave/row), fp32 in, bf16 out ----------
__global__ __launch_bounds__(256)
void ln_kernel(const float* __restrict__ x, const float* __restrict__ w,
               const float* __restrict__ b, bf16* __restrict__ out) {
    int row = blockIdx.x * 4 + (threadIdx.x >> 6);
    int t = threadIdx.x & 63;
    const float* xr = x + (size_t)row * DIMC;
    float vals[6];
    float s = 0.f;
    #pragma unroll
    for (int i = 0; i < 6; i++) { vals[i] = xr[t + i*64]; s += vals[i]; }
    #pragma unroll
    for (int m = 32; m; m >>= 1) s += __shfl_xor(s, m);
    float mean = s * (1.0f / DIMC);
    float sq = 0.f;
    #pragma unroll
    for (int i = 0; i < 6; i++) { float d = vals[i] - mean; sq += d * d; }
    #pragma unroll
    for (int m = 32; m; m >>= 1) sq += __shfl_xor(sq, m);
    float rstd = rsqrtf(sq * (1.0f / DIMC) + 1e-5f);
    bf16* orow = out + (size_t)row * DIMC;
    #pragma unroll
    for (int i = 0; i < 6; i++) {
        int c = t + i*64;
        orow[c] = (bf16)((vals[i] - mean) * rstd * w[c] + b[c]);
    }
}

// ---- fused: x1 = x + Pp0 + Pp1 + proj_b (write fp32 x1) ; h = LN2(x1) (write bf16) ----
__global__ __launch_bounds__(256)
void ln2_fused(const float* __restrict__ x, const bf16* __restrict__ p0,
               const bf16* __restrict__ p1, const float* __restrict__ pb,
               const float* __restrict__ w, const float* __restrict__ b,
               float* __restrict__ x1, bf16* __restrict__ h) {
    int row = blockIdx.x * 4 + (threadIdx.x >> 6);
    int t = threadIdx.x & 63;
    size_t base = (size_t)row * DIMC;
    float vals[6];
    float s = 0.f;
    #pragma unroll
    for (int i = 0; i < 6; i++) {
        int c = t + i*64;
        float v = x[base + c] + (float)p0[base + c] + (float)p1[base + c] + pb[c];
        vals[i] = v; s += v;
    }
    #pragma unroll
    for (int m = 32; m; m >>= 1) s += __shfl_xor(s, m);
    float mean = s * (1.0f / DIMC);
    float sq = 0.f;
    #pragma unroll
    for (int i = 0; i < 6; i++) { float d = vals[i] - mean; sq += d * d; }
    #pragma unroll
    for (int m = 32; m; m >>= 1) sq += __shfl_xor(sq, m);
    float rstd = rsqrtf(sq * (1.0f / DIMC) + 1e-5f);
    #pragma unroll
    for (int i = 0; i < 6; i++) {
        int c = t + i*64;
        x1[base + c] = vals[i];
        h[base + c] = (bf16)((vals[i] - mean) * rstd * w[c] + b[c]);
    }
}

// ---- final: out = x1 + b2 + Pm0+Pm1+Pm2+Pm3 (bf16 partials), float4-vectorized ----
__global__ __launch_bounds__(256)
void reduce4(float* __restrict__ xo, const bf16* __restrict__ p0, const bf16* __restrict__ p1,
             const bf16* __restrict__ p2, const bf16* __restrict__ p3,
             const float* __restrict__ b2) {
    int i = blockIdx.x * 256 + threadIdx.x;   // float4 index, < TC/4
    float4 v = ((const float4*)xo)[i];
    int c = (i % 96) * 4;
    float4 bb = *(const float4*)(b2 + c);
    bf16x4 a0 = ((const bf16x4*)p0)[i], a1 = ((const bf16x4*)p1)[i];
    bf16x4 a2 = ((const bf16x4*)p2)[i], a3 = ((const bf16x4*)p3)[i];
    v.x += bb.x + (float)a0[0] + (float)a1[0] + (float)a2[0] + (float)a3[0];
    v.y += bb.y + (float)a0[1] + (float)a1[1] + (float)a2[1] + (float)a3[1];
    v.z += bb.z + (float)a0[2] + (float)a1[2] + (float)a2[2] + (float)a3[2];
    v.w += bb.w + (float)a0[3] + (float)a1[3] + (float)a2[3] + (float)a3[3];
    ((float4*)xo)[i] = v;
}

// ---------------- GEMM: C[M,N] = A[M,K] @ W[N,K]^T, m97-style LDS staging ----------------
enum { EPI_NONE = 0, EPI_QKV = 1, EPI_GELU = 3 };

template<int EPI, int K, int KS, typename OutT>
__global__ __launch_bounds__(256)
void gemm_bt(const bf16* __restrict__ A, const bf16* __restrict__ W,
             const float* __restrict__ bias, OutT* out, int M, int N) {
    __shared__ __align__(16) bf16 Ash[128*32];
    __shared__ __align__(16) bf16 Bsh[128*32];
    constexpr int KB = K / KS;               // K extent per block
    int tid = threadIdx.x;
    int lane = tid & 63, w = tid >> 6;
    int quad = lane >> 4, l16 = lane & 15;
    int rbase = blockIdx.y * 128 + (w >> 1) * 64;
    int cbase = blockIdx.x * 128 + (w & 1) * 64;
    int kbase = blockIdx.z * KB;
    int c1 = w * 64 + lane;                  // [0,256)
    int c2 = c1 + 256;                       // [256,512)
    const bf16* Ag1 = A + (size_t)(blockIdx.y*128 + (c1 >> 2)) * K + kbase + (c1 & 3) * 8;
    const bf16* Ag2 = A + (size_t)(blockIdx.y*128 + (c2 >> 2)) * K + kbase + (c2 & 3) * 8;
    const bf16* Wg1 = W + (size_t)(blockIdx.x*128 + (c1 >> 2)) * K + kbase + (c1 & 3) * 8;
    const bf16* Wg2 = W + (size_t)(blockIdx.x*128 + (c2 >> 2)) * K + kbase + (c2 & 3) * 8;
    bf16* As1 = Ash + c1 * 8;  bf16* As2 = Ash + c2 * 8;
    bf16* Bs1 = Bsh + c1 * 8;  bf16* Bs2 = Bsh + c2 * 8;

    int arow = (w >> 1) * 64;                // wave's row offset within tile
    int brow = (w & 1) * 64;
    floatx4 acc[4][4] = {};
    #pragma unroll
    for (int kk = 0; kk < KB / 32; kk++) {
        __syncthreads();                     // prev iter's LDS reads complete
        async_cp16(Ag1 + kk*32, As1);
        async_cp16(Ag2 + kk*32, As2);
        async_cp16(Wg1 + kk*32, Bs1);
        async_cp16(Wg2 + kk*32, Bs2);
        __syncthreads();                     // drains vmcnt (lds-DMA) + lgkmcnt
        bf16x8 a[4], bfr[4];
        #pragma unroll
        for (int tm = 0; tm < 4; tm++)
            a[tm] = *(const bf16x8*)&Ash[(arow + tm*16 + l16) * 32 + quad*8];
        #pragma unroll
        for (int tn = 0; tn < 4; tn++)
            bfr[tn] = *(const bf16x8*)&Bsh[(brow + tn*16 + l16) * 32 + quad*8];
        #pragma unroll
        for (int tm = 0; tm < 4; tm++)
            #pragma unroll
            for (int tn = 0; tn < 4; tn++)
                acc[tm][tn] = __builtin_amdgcn_mfma_f32_16x16x32_bf16(a[tm], bfr[tn], acc[tm][tn], 0, 0, 0);
    }

    #pragma unroll
    for (int tm = 0; tm < 4; tm++)
        #pragma unroll
        for (int tn = 0; tn < 4; tn++) {
            if constexpr (EPI == EPI_QKV) {
                int colb = cbase + tn*16 + l16;       // uniform 'which' per tile (384%16==0)
                int which = colb / 384;
                int rowb = rbase + tm*16 + quad*4;
                int bb = rowb >> 10;
                if (which == 2) {
                    // V transposed: [B,H,D,N]; 4 consecutive n -> packed 8B store
                    int rem = colb - 768;
                    int hh = rem >> 6, d = rem & 63;
                    int n = rowb & 1023;
                    bf16x4 pk;
                    #pragma unroll
                    for (int r = 0; r < 4; r++) pk[r] = (bf16)acc[tm][tn][r];
                    *(bf16x4*)((bf16*)out + 2*TC + (((size_t)(bb*NH + hh) * HD + d) << 10) + n) = pk;
                } else {
                    int rem = colb - which*384;
                    int hh = rem >> 6, d = rem & 63;
                    #pragma unroll
                    for (int r = 0; r < 4; r++) {
                        int n = (rowb & 1023) + r;
                        ((bf16*)out)[(size_t)which*TC + (((size_t)(bb*NH + hh) * SEQ + n) << 6) + d]
                            = (bf16)acc[tm][tn][r];
                    }
                }
            } else if constexpr (EPI == EPI_NONE) {
                OutT* ob = out + (size_t)blockIdx.z * M * N;
                #pragma unroll
                for (int r = 0; r < 4; r++) {
                    int row = rbase + tm*16 + quad*4 + r;
                    int col = cbase + tn*16 + l16;
                    ob[(size_t)row * N + col] = (OutT)acc[tm][tn][r];
                }
            } else {  // EPI_GELU
                #pragma unroll
                for (int r = 0; r < 4; r++) {
                    int row = rbase + tm*16 + quad*4 + r;
                    int col = cbase + tn*16 + l16;
                    float v = acc[tm][tn][r] + bias[col];
                    v = 0.5f * v * (1.0f + erff(v * 0.70710678118f));
                    out[(size_t)row * N + col] = (OutT)v;
                }
            }
        }
}

// ---------------- Fused L2Q attention, restructured (round 4) ----------------
// Wave decomposition fix: QK^T splits K across waves (swapped-operand mfma(K,Q) ->
// lane holds 4 consecutive k for one q-row -> packed ds_write_b64 P-stores, rowsum
// as free lane-local VALU adds). P chunk [64 q][256 k] is block-shared in LDS; PV
// splits the D dimension across waves (o[4] = 16 VGPR accumulator, no cross-wave
// epilogue reduction). Q reloaded per-qsub from L1 (8KB tile). Nominal peak live
// ~116 VGPR -> no spill; launch_bounds(256,2) caps at 128 (arg appears to be in
// wave32 units: (256,4) produced a 64-VGPR cap + spill in round 3).
__global__ __launch_bounds__(256, 2)
void attn_kernel(const bf16* __restrict__ q, const bf16* __restrict__ k,
                 const bf16* __restrict__ vt, const float* __restrict__ alpha,
                 const float* __restrict__ beta, const float* __restrict__ gamma,
                 bf16* __restrict__ attn_out) {
    __shared__ __align__(16) bf16 Psh[64][264];   // 33792 B, pitch 528 B (bank-balanced)
    __shared__ float rsW[4][64];                  // per-wave rowsum partials
    __shared__ float rs_final[64];

    int L = blockIdx.x;
    int xcd = L & 7, slot = L >> 3;               // slot in [0,96)
    int qt = slot & 15;                           // 16 q-tiles of 64 rows
    int bh = xcd + ((slot >> 4) << 3);            // {xcd, xcd+8, ..., xcd+40}
    int bb = bh / NH, h = bh % NH;
    int q0 = qt * 64;
    int tid = threadIdx.x;
    int w = tid >> 6, lane = tid & 63, quad = lane >> 4, l16 = lane & 15;
    float av = alpha[h] * (QK_SCALE * QK_SCALE), bv = beta[h] * QK_SCALE, gv = gamma[h];
    const bf16* qb  = q  + (size_t)bh * SEQ * HD;
    const bf16* kb  = k  + (size_t)bh * SEQ * HD;
    const bf16* vtb = vt + (size_t)bh * HD * SEQ;

    floatx4 o[4] = {};                            // wave's d-slice [w*16, w*16+16), 4 q-subtiles
    float rsp[4] = {0.f, 0.f, 0.f, 0.f};          // lane-local rowsum partials per q-subtile

    bf16x8 kf[2][4];
    // prologue: K fragments for chunk 0 (wave w covers k in [w*64, w*64+64))
    #pragma unroll
    for (int ks = 0; ks < 2; ks++)
        #pragma unroll
        for (int ksub = 0; ksub < 4; ksub++)
            kf[ks][ksub] = *(const bf16x8*)(kb + (size_t)(w*64 + ksub*16 + l16) * HD + ks*32 + quad*8);

    for (int c = 0; c < 4; c++) {
        // ---- QK^T (swapped operands) + quadratic relu + packed P store + rs ----
        #pragma unroll
        for (int qsub = 0; qsub < 4; qsub++) {
            bf16x8 qa0 = *(const bf16x8*)(qb + (size_t)(q0 + qsub*16 + l16) * HD + quad*8);
            bf16x8 qa1 = *(const bf16x8*)(qb + (size_t)(q0 + qsub*16 + l16) * HD + 32 + quad*8);
            floatx4 s[4] = {};
            #pragma unroll
            for (int ksub = 0; ksub < 4; ksub++)
                s[ksub] = __builtin_amdgcn_mfma_f32_16x16x32_bf16(kf[0][ksub], qa0, s[ksub], 0, 0, 0);
            #pragma unroll
            for (int ksub = 0; ksub < 4; ksub++)
                s[ksub] = __builtin_amdgcn_mfma_f32_16x16x32_bf16(kf[1][ksub], qa1, s[ksub], 0, 0, 0);
            #pragma unroll
            for (int ksub = 0; ksub < 4; ksub++) {
                bf16x4 p4;
                float rsum = 0.f;
                #pragma unroll
                for (int r = 0; r < 4; r++) {
                    float xx = s[ksub][r];
                    float p = fmaxf((av*xx + bv)*xx + gv, 0.f);
                    p4[r] = (bf16)p;
                    rsum += p;
                }
                rsp[qsub] += rsum;
                // lane owns q-row (qsub*16+l16), k = w*64 + ksub*16 + quad*4 .. +4
                *(bf16x4*)&Psh[qsub*16 + l16][w*64 + ksub*16 + quad*4] = p4;
            }
        }
        __syncthreads();                          // P chunk ready
        // prefetch next chunk's K fragments (land during PV phase)
        if (c < 3) {
            int kc = (c+1)*256 + w*64;
            #pragma unroll
            for (int ks = 0; ks < 2; ks++)
                #pragma unroll
                for (int ksub = 0; ksub < 4; ksub++)
                    kf[ks][ksub] = *(const bf16x8*)(kb + (size_t)(kc + ksub*16 + l16) * HD + ks*32 + quad*8);
        }
        // ---- PV: wave w owns d-cols [w*16, w*16+16) over this chunk's 256 k ----
        const bf16* vrow = vtb + (size_t)(w*16 + l16) * SEQ + c*256;
        #pragma unroll
        for (int ksl = 0; ksl < 8; ksl++) {
            bf16x8 vf = *(const bf16x8*)(vrow + ksl*32 + quad*8);
            #pragma unroll
            for (int qsub = 0; qsub < 4; qsub++) {
                bf16x8 pf = *(const bf16x8*)&Psh[qsub*16 + l16][ksl*32 + quad*8];
                o[qsub] = __builtin_amdgcn_mfma_f32_16x16x32_bf16(pf, vf, o[qsub], 0, 0, 0);
            }
        }
        __syncthreads();                          // PV reads done; safe to overwrite P
    }

    // ---- rowsum finalize: quad-reduce (lanes l16, l16+16, +32, +48 share a q-row) ----
    #pragma unroll
    for (int qsub = 0; qsub < 4; qsub++) {
        rsp[qsub] += __shfl_xor(rsp[qsub], 16);
        rsp[qsub] += __shfl_xor(rsp[qsub], 32);
    }
    if (quad == 0) {
        #pragma unroll
        for (int qsub = 0; qsub < 4; qsub++)
            rsW[w][qsub*16 + l16] = rsp[qsub];
    }
    __syncthreads();
    if (tid < 64)
        rs_final[tid] = rsW[0][tid] + rsW[1][tid] + rsW[2][tid] + rsW[3][tid] + 1e-6f;
    __syncthreads();

    // ---- divide + store: wave w stores its d-slice for all 64 q rows ----
    #pragma unroll
    for (int qsub = 0; qsub < 4; qsub++)
        #pragma unroll
        for (int r = 0; r < 4; r++) {
            int ql = qsub*16 + quad*4 + r;
            float rv = rs_final[ql];              // broadcast read (same addr across l16)
            int n = q0 + ql;
            attn_out[((size_t)(bb*SEQ + n)) * DIMC + h*HD + w*16 + l16] =
                (bf16)(o[qsub][r] / rv);
        }
}

// ---------------- driver ----------------
extern "C" void kernel_launch(void* const* d_in, const int* in_sizes, int n_in,
                              void* d_out, int out_size, void* d_ws, size_t ws_size,
                              hipStream_t stream) {
    const float* x      = (const float*)d_in[0];
    const float* qkv_w  = (const float*)d_in[1];
    const float* proj_w = (const float*)d_in[2];
    const float* proj_b = (const float*)d_in[3];
    const float* alpha  = (const float*)d_in[4];
    const float* beta   = (const float*)d_in[5];
    const float* gamma  = (const float*)d_in[6];
    const float* ln1_w  = (const float*)d_in[7];
    const float* ln1_b  = (const float*)d_in[8];
    const float* ln2_w  = (const float*)d_in[9];
    const float* ln2_b  = (const float*)d_in[10];
    const float* w1     = (const float*)d_in[11];
    const float* b1     = (const float*)d_in[12];
    const float* w2     = (const float*)d_in[13];
    const float* b2     = (const float*)d_in[14];
    float* out = (float*)d_out;           // fp32 output; also doubles as x1 buffer

    // ws layout unchanged (see journal)
    char* base = (char*)d_ws;
    bf16* wq_bf = (bf16*)base;                 // 1152x384
    bf16* wp_bf = wq_bf + 442368;              // 384x384
    bf16* w1_bf = wq_bf + 589824;              // 1536x384
    bf16* w2_bf = wq_bf + 1179648;             // 384x1536
    bf16* h      = (bf16*)(base + 3538944);
    bf16* qkv    = (bf16*)(base + 9830400);
    bf16* attn_o = (bf16*)(base + 28704768);
    bf16* m      = qkv;                        // overlays qkv+attn_o (both dead by mlp1)
    bf16* Pp     = (bf16*)(base + 34996224);   // 2*TC (proj split-K partials)
    bf16* Pm     = (bf16*)(base + 34996224);   // 4*TC (mlp2 split-K partials; Pp dead)

    cvt_all<<<1728, 256, 0, stream>>>(qkv_w, proj_w, w1, w2, wq_bf);
    ln_kernel<<<T_TOK/4, 256, 0, stream>>>(x, ln1_w, ln1_b, h);
    gemm_bt<EPI_QKV, 384, 1, bf16><<<dim3(9, 64, 1), 256, 0, stream>>>(
        h, wq_bf, nullptr, qkv, T_TOK, 1152);
    attn_kernel<<<768, 256, 0, stream>>>(
        qkv, qkv + TC, qkv + 2*TC, alpha, beta, gamma, attn_o);
    gemm_bt<EPI_NONE, 384, 2, bf16><<<dim3(3, 64, 2), 256, 0, stream>>>(
        attn_o, wp_bf, nullptr, Pp, T_TOK, DIMC);
    ln2_fused<<<T_TOK/4, 256, 0, stream>>>(x, Pp, Pp + TC, proj_b, ln2_w, ln2_b, out, h);
    gemm_bt<EPI_GELU, 384, 1, bf16><<<dim3(12, 64, 1), 256, 0, stream>>>(
        h, w1_bf, b1, m, T_TOK, MLPD);
    gemm_bt<EPI_NONE, 1536, 4, bf16><<<dim3(3, 64, 4), 256, 0, stream>>>(
        m, w2_bf, nullptr, Pm, T_TOK, DIMC);
    reduce4<<<TC/4/256, 256, 0, stream>>>(out, Pm, Pm + TC, Pm + 2*TC, Pm + 3*TC, b2);
}

// Round 6
// 225.306 us; speedup vs baseline: 1.0653x; 1.0143x over previous
//
#include <hip/hip_runtime.h>
#include <hip/hip_bf16.h>
#include <math.h>

#define DIMC 384
#define NH 6
#define HD 64
#define MLPD 1536
#define BS 8
#define SEQ 1024
#define T_TOK (BS*SEQ)                  // 8192 tokens
#define TC ((size_t)T_TOK*DIMC)         // 3,145,728 elems
#define QK_SCALE 0.125f                 // 64^-0.5

typedef __bf16 bf16;
typedef bf16 bf16x4 __attribute__((ext_vector_type(4)));
typedef bf16 bf16x8 __attribute__((ext_vector_type(8)));
typedef float floatx4 __attribute__((ext_vector_type(4)));

// async global->LDS 16B (per-lane LDS dest must equal wave-uniform-base + lane*16)
__device__ __forceinline__ void async_cp16(const void* gsrc, void* ldst) {
    __builtin_amdgcn_global_load_lds(
        (const __attribute__((address_space(1))) unsigned int*)gsrc,
        (__attribute__((address_space(3))) unsigned int*)ldst,
        16, 0, 0);
}

// ---- merged: fp32->bf16 weight cvt (blocks 0..1727) | LN1 (blocks 1728..3775) ----
__global__ __launch_bounds__(256)
void prep_kernel(const float* __restrict__ s0, const float* __restrict__ s1,
                 const float* __restrict__ s2, const float* __restrict__ s3,
                 bf16* __restrict__ dst,
                 const float* __restrict__ x, const float* __restrict__ lw,
                 const float* __restrict__ lb, bf16* __restrict__ out) {
    if (blockIdx.x < 1728) {
        int i = blockIdx.x * 256 + threadIdx.x;   // i < 442368 float4 chunks
        const int n0 = 110592, n1 = 36864, n2 = 147456;   // float4 counts
        const float4* src; int j;
        if (i < n0)           { src = (const float4*)s0; j = i; }
        else if (i < n0+n1)   { src = (const float4*)s1; j = i - n0; }
        else if (i < n0+n1+n2){ src = (const float4*)s2; j = i - n0 - n1; }
        else                  { src = (const float4*)s3; j = i - n0 - n1 - n2; }
        float4 v = src[j];
        bf16x4 o; o[0] = (bf16)v.x; o[1] = (bf16)v.y; o[2] = (bf16)v.z; o[3] = (bf16)v.w;
        ((bf16x4*)dst)[i] = o;
    } else {
        int row = (blockIdx.x - 1728) * 4 + (threadIdx.x >> 6);
        int t = threadIdx.x & 63;
        const float* xr = x + (size_t)row * DIMC;
        float vals[6];
        float s = 0.f;
        #pragma unroll
        for (int i = 0; i < 6; i++) { vals[i] = xr[t + i*64]; s += vals[i]; }
        #pragma unroll
        for (int m = 32; m; m >>= 1) s += __shfl_xor(s, m);
        float mean = s * (1.0f / DIMC);
        float sq = 0.f;
        #pragma unroll
        for (int i = 0; i < 6; i++) { float d = vals[i] - mean; sq += d * d; }
        #pragma unroll
        for (int m = 32; m; m >>= 1) sq += __shfl_xor(sq, m);
        float rstd = rsqrtf(sq * (1.0f / DIMC) + 1e-5f);
        bf16* orow = out + (size_t)row * DIMC;
        #pragma unroll
        for (int i = 0; i < 6; i++) {
            int c = t + i*64;
            orow[c] = (bf16)((vals[i] - mean) * rstd * lw[c] + lb[c]);
        }
    }
}

// ---- fused: x1 = x + Pp0 + Pp1 + proj_b (write fp32 x1) ; h = LN2(x1) (write bf16) ----
__global__ __launch_bounds__(256)
void ln2_fused(const float* __restrict__ x, const bf16* __restrict__ p0,
               const bf16* __restrict__ p1, const float* __restrict__ pb,
               const float* __restrict__ w, const float* __restrict__ b,
               float* __restrict__ x1, bf16* __restrict__ h) {
    int row = blockIdx.x * 4 + (threadIdx.x >> 6);
    int t = threadIdx.x & 63;
    size_t base = (size_t)row * DIMC;
    float vals[6];
    float s = 0.f;
    #pragma unroll
    for (int i = 0; i < 6; i++) {
        int c = t + i*64;
        float v = x[base + c] + (float)p0[base + c] + (float)p1[base + c] + pb[c];
        vals[i] = v; s += v;
    }
    #pragma unroll
    for (int m = 32; m; m >>= 1) s += __shfl_xor(s, m);
    float mean = s * (1.0f / DIMC);
    float sq = 0.f;
    #pragma unroll
    for (int i = 0; i < 6; i++) { float d = vals[i] - mean; sq += d * d; }
    #pragma unroll
    for (int m = 32; m; m >>= 1) sq += __shfl_xor(sq, m);
    float rstd = rsqrtf(sq * (1.0f / DIMC) + 1e-5f);
    #pragma unroll
    for (int i = 0; i < 6; i++) {
        int c = t + i*64;
        x1[base + c] = vals[i];
        h[base + c] = (bf16)((vals[i] - mean) * rstd * w[c] + b[c]);
    }
}

// ---- final: out = x1 + b2 + Pm0+Pm1+Pm2+Pm3 (bf16 partials), float4-vectorized ----
__global__ __launch_bounds__(256)
void reduce4(float* __restrict__ xo, const bf16* __restrict__ p0, const bf16* __restrict__ p1,
             const bf16* __restrict__ p2, const bf16* __restrict__ p3,
             const float* __restrict__ b2) {
    int i = blockIdx.x * 256 + threadIdx.x;   // float4 index, < TC/4
    float4 v = ((const float4*)xo)[i];
    int c = (i % 96) * 4;
    float4 bb = *(const float4*)(b2 + c);
    bf16x4 a0 = ((const bf16x4*)p0)[i], a1 = ((const bf16x4*)p1)[i];
    bf16x4 a2 = ((const bf16x4*)p2)[i], a3 = ((const bf16x4*)p3)[i];
    v.x += bb.x + (float)a0[0] + (float)a1[0] + (float)a2[0] + (float)a3[0];
    v.y += bb.y + (float)a0[1] + (float)a1[1] + (float)a2[1] + (float)a3[1];
    v.z += bb.z + (float)a0[2] + (float)a1[2] + (float)a2[2] + (float)a3[2];
    v.w += bb.w + (float)a0[3] + (float)a1[3] + (float)a2[3] + (float)a3[3];
    ((float4*)xo)[i] = v;
}

// ---------------- GEMM: C[M,N] = A[M,K] @ W[N,K]^T, m97-style LDS staging ----------------
enum { EPI_NONE = 0, EPI_QKV = 1, EPI_GELU = 3 };

template<int EPI, int K, int KS, typename OutT>
__global__ __launch_bounds__(256)
void gemm_bt(const bf16* __restrict__ A, const bf16* __restrict__ W,
             const float* __restrict__ bias, OutT* out, int M, int N) {
    __shared__ __align__(16) bf16 Ash[128*32];
    __shared__ __align__(16) bf16 Bsh[128*32];
    constexpr int KB = K / KS;               // K extent per block
    int tid = threadIdx.x;
    int lane = tid & 63, w = tid >> 6;
    int quad = lane >> 4, l16 = lane & 15;
    int rbase = blockIdx.y * 128 + (w >> 1) * 64;
    int cbase = blockIdx.x * 128 + (w & 1) * 64;
    int kbase = blockIdx.z * KB;
    int c1 = w * 64 + lane;                  // [0,256)
    int c2 = c1 + 256;                       // [256,512)
    const bf16* Ag1 = A + (size_t)(blockIdx.y*128 + (c1 >> 2)) * K + kbase + (c1 & 3) * 8;
    const bf16* Ag2 = A + (size_t)(blockIdx.y*128 + (c2 >> 2)) * K + kbase + (c2 & 3) * 8;
    const bf16* Wg1 = W + (size_t)(blockIdx.x*128 + (c1 >> 2)) * K + kbase + (c1 & 3) * 8;
    const bf16* Wg2 = W + (size_t)(blockIdx.x*128 + (c2 >> 2)) * K + kbase + (c2 & 3) * 8;
    bf16* As1 = Ash + c1 * 8;  bf16* As2 = Ash + c2 * 8;
    bf16* Bs1 = Bsh + c1 * 8;  bf16* Bs2 = Bsh + c2 * 8;

    int arow = (w >> 1) * 64;                // wave's row offset within tile
    int brow = (w & 1) * 64;
    floatx4 acc[4][4] = {};
    #pragma unroll
    for (int kk = 0; kk < KB / 32; kk++) {
        __syncthreads();                     // prev iter's LDS reads complete
        async_cp16(Ag1 + kk*32, As1);
        async_cp16(Ag2 + kk*32, As2);
        async_cp16(Wg1 + kk*32, Bs1);
        async_cp16(Wg2 + kk*32, Bs2);
        __syncthreads();                     // drains vmcnt (lds-DMA) + lgkmcnt
        bf16x8 a[4], bfr[4];
        #pragma unroll
        for (int tm = 0; tm < 4; tm++)
            a[tm] = *(const bf16x8*)&Ash[(arow + tm*16 + l16) * 32 + quad*8];
        #pragma unroll
        for (int tn = 0; tn < 4; tn++)
            bfr[tn] = *(const bf16x8*)&Bsh[(brow + tn*16 + l16) * 32 + quad*8];
        #pragma unroll
        for (int tm = 0; tm < 4; tm++)
            #pragma unroll
            for (int tn = 0; tn < 4; tn++)
                acc[tm][tn] = __builtin_amdgcn_mfma_f32_16x16x32_bf16(a[tm], bfr[tn], acc[tm][tn], 0, 0, 0);
    }

    #pragma unroll
    for (int tm = 0; tm < 4; tm++)
        #pragma unroll
        for (int tn = 0; tn < 4; tn++) {
            if constexpr (EPI == EPI_QKV) {
                int colb = cbase + tn*16 + l16;       // uniform 'which' per tile (384%16==0)
                int which = colb / 384;
                int rowb = rbase + tm*16 + quad*4;
                int bb = rowb >> 10;
                if (which == 2) {
                    // V transposed: [B,H,D,N]; 4 consecutive n -> packed 8B store
                    int rem = colb - 768;
                    int hh = rem >> 6, d = rem & 63;
                    int n = rowb & 1023;
                    bf16x4 pk;
                    #pragma unroll
                    for (int r = 0; r < 4; r++) pk[r] = (bf16)acc[tm][tn][r];
                    *(bf16x4*)((bf16*)out + 2*TC + (((size_t)(bb*NH + hh) * HD + d) << 10) + n) = pk;
                } else {
                    int rem = colb - which*384;
                    int hh = rem >> 6, d = rem & 63;
                    #pragma unroll
                    for (int r = 0; r < 4; r++) {
                        int n = (rowb & 1023) + r;
                        ((bf16*)out)[(size_t)which*TC + (((size_t)(bb*NH + hh) * SEQ + n) << 6) + d]
                            = (bf16)acc[tm][tn][r];
                    }
                }
            } else if constexpr (EPI == EPI_NONE) {
                OutT* ob = out + (size_t)blockIdx.z * M * N;
                #pragma unroll
                for (int r = 0; r < 4; r++) {
                    int row = rbase + tm*16 + quad*4 + r;
                    int col = cbase + tn*16 + l16;
                    ob[(size_t)row * N + col] = (OutT)acc[tm][tn][r];
                }
            } else {  // EPI_GELU
                #pragma unroll
                for (int r = 0; r < 4; r++) {
                    int row = rbase + tm*16 + quad*4 + r;
                    int col = cbase + tn*16 + l16;
                    float v = acc[tm][tn][r] + bias[col];
                    v = 0.5f * v * (1.0f + erff(v * 0.70710678118f));
                    out[(size_t)row * N + col] = (OutT)v;
                }
            }
        }
}

// ---------------- Fused L2Q attention (round 5, resubmitted unchanged) ----------------
// (1) Psh pitch 264 -> 260 elem (130 dw === 2 mod 4): P access as b64 pairs is
// bank-capacity-optimal (old pitch gave 8-way conflicts on ds_read_b128,
// SQ_LDS_BANK_CONFLICT 2.36M). (2) V fragments depth-1 prefetched: chunk c+1's
// vf[8] issued after PV(c) consumes vf, covered by the chunk barrier + next QK^T
// phase. (3) plain launch_bounds(256): grid supplies only 3 blocks/CU, so VGPR up
// to ~170 keeps 3 waves/SIMD; forcing a cap risks spill (round-3 lesson: 2nd arg
// N caps VGPR at 512/(2N)).
__global__ __launch_bounds__(256)
void attn_kernel(const bf16* __restrict__ q, const bf16* __restrict__ k,
                 const bf16* __restrict__ vt, const float* __restrict__ alpha,
                 const float* __restrict__ beta, const float* __restrict__ gamma,
                 bf16* __restrict__ attn_out) {
    __shared__ __align__(16) bf16 Psh[64][260];   // pitch 520B
    __shared__ float rsW[4][64];                  // per-wave rowsum partials
    __shared__ float rs_final[64];

    int L = blockIdx.x;
    int xcd = L & 7, slot = L >> 3;               // slot in [0,96)
    int qt = slot & 15;                           // 16 q-tiles of 64 rows
    int bh = xcd + ((slot >> 4) << 3);            // {xcd, xcd+8, ..., xcd+40}
    int bb = bh / NH, h = bh % NH;
    int q0 = qt * 64;
    int tid = threadIdx.x;
    int w = tid >> 6, lane = tid & 63, quad = lane >> 4, l16 = lane & 15;
    float av = alpha[h] * (QK_SCALE * QK_SCALE), bv = beta[h] * QK_SCALE, gv = gamma[h];
    const bf16* qb  = q  + (size_t)bh * SEQ * HD;
    const bf16* kb  = k  + (size_t)bh * SEQ * HD;
    const bf16* vtb = vt + (size_t)bh * HD * SEQ;

    floatx4 o[4] = {};                            // wave's d-slice [w*16, w*16+16)
    float rsp[4] = {0.f, 0.f, 0.f, 0.f};          // lane-local rowsum partials

    bf16x8 kf[2][4], vf[8];
    // prologue: chunk-0 K fragments (wave w covers k in [w*64, w*64+64))
    #pragma unroll
    for (int ks = 0; ks < 2; ks++)
        #pragma unroll
        for (int ksub = 0; ksub < 4; ksub++)
            kf[ks][ksub] = *(const bf16x8*)(kb + (size_t)(w*64 + ksub*16 + l16) * HD + ks*32 + quad*8);
    // prologue: chunk-0 V fragments (wave w owns d-rows [w*16, w*16+16))
    const bf16* vrow = vtb + (size_t)(w*16 + l16) * SEQ;
    #pragma unroll
    for (int ksl = 0; ksl < 8; ksl++)
        vf[ksl] = *(const bf16x8*)(vrow + ksl*32 + quad*8);

    for (int c = 0; c < 4; c++) {
        // ---- QK^T (swapped operands) + quadratic relu + packed b64 P store + rs ----
        #pragma unroll
        for (int qsub = 0; qsub < 4; qsub++) {
            bf16x8 qa0 = *(const bf16x8*)(qb + (size_t)(q0 + qsub*16 + l16) * HD + quad*8);
            bf16x8 qa1 = *(const bf16x8*)(qb + (size_t)(q0 + qsub*16 + l16) * HD + 32 + quad*8);
            floatx4 s[4] = {};
            #pragma unroll
            for (int ksub = 0; ksub < 4; ksub++)
                s[ksub] = __builtin_amdgcn_mfma_f32_16x16x32_bf16(kf[0][ksub], qa0, s[ksub], 0, 0, 0);
            #pragma unroll
            for (int ksub = 0; ksub < 4; ksub++)
                s[ksub] = __builtin_amdgcn_mfma_f32_16x16x32_bf16(kf[1][ksub], qa1, s[ksub], 0, 0, 0);
            #pragma unroll
            for (int ksub = 0; ksub < 4; ksub++) {
                bf16x4 p4;
                float rsum = 0.f;
                #pragma unroll
                for (int r = 0; r < 4; r++) {
                    float xx = s[ksub][r];
                    float p = fmaxf((av*xx + bv)*xx + gv, 0.f);
                    p4[r] = (bf16)p;
                    rsum += p;
                }
                rsp[qsub] += rsum;
                // lane owns q-row (qsub*16+l16), k = w*64 + ksub*16 + quad*4 .. +4
                *(bf16x4*)&Psh[qsub*16 + l16][w*64 + ksub*16 + quad*4] = p4;
            }
        }
        __syncthreads();                          // P chunk ready
        // prefetch next chunk's K fragments (land during PV phase)
        if (c < 3) {
            int kc = (c+1)*256 + w*64;
            #pragma unroll
            for (int ks = 0; ks < 2; ks++)
                #pragma unroll
                for (int ksub = 0; ksub < 4; ksub++)
                    kf[ks][ksub] = *(const bf16x8*)(kb + (size_t)(kc + ksub*16 + l16) * HD + ks*32 + quad*8);
        }
        // ---- PV: wave w owns d-cols [w*16, w*16+16) over this chunk's 256 k ----
        #pragma unroll
        for (int ksl = 0; ksl < 8; ksl++) {
            #pragma unroll
            for (int qsub = 0; qsub < 4; qsub++) {
                // P read as two b64s (row pitch 520B is 8B-aligned, bank-uniform)
                bf16x4 plo = *(const bf16x4*)&Psh[qsub*16 + l16][ksl*32 + quad*8];
                bf16x4 phi = *(const bf16x4*)&Psh[qsub*16 + l16][ksl*32 + quad*8 + 4];
                bf16x8 pf = __builtin_shufflevector(plo, phi, 0, 1, 2, 3, 4, 5, 6, 7);
                o[qsub] = __builtin_amdgcn_mfma_f32_16x16x32_bf16(pf, vf[ksl], o[qsub], 0, 0, 0);
            }
        }
        // prefetch next chunk's V fragments (vf consumed; covered by barrier + QK^T)
        if (c < 3) {
            const bf16* vr2 = vrow + (c+1)*256;
            #pragma unroll
            for (int ksl = 0; ksl < 8; ksl++)
                vf[ksl] = *(const bf16x8*)(vr2 + ksl*32 + quad*8);
        }
        __syncthreads();                          // PV reads done; safe to overwrite P
    }

    // ---- rowsum finalize: quad-reduce (lanes l16, l16+16, +32, +48 share a q-row) ----
    #pragma unroll
    for (int qsub = 0; qsub < 4; qsub++) {
        rsp[qsub] += __shfl_xor(rsp[qsub], 16);
        rsp[qsub] += __shfl_xor(rsp[qsub], 32);
    }
    if (quad == 0) {
        #pragma unroll
        for (int qsub = 0; qsub < 4; qsub++)
            rsW[w][qsub*16 + l16] = rsp[qsub];
    }
    __syncthreads();
    if (tid < 64)
        rs_final[tid] = rsW[0][tid] + rsW[1][tid] + rsW[2][tid] + rsW[3][tid] + 1e-6f;
    __syncthreads();

    // ---- divide + store: wave w stores its d-slice for all 64 q rows ----
    #pragma unroll
    for (int qsub = 0; qsub < 4; qsub++)
        #pragma unroll
        for (int r = 0; r < 4; r++) {
            int ql = qsub*16 + quad*4 + r;
            float rv = rs_final[ql];              // broadcast read (same addr across l16)
            int n = q0 + ql;
            attn_out[((size_t)(bb*SEQ + n)) * DIMC + h*HD + w*16 + l16] =
                (bf16)(o[qsub][r] / rv);
        }
}

// ---------------- driver ----------------
extern "C" void kernel_launch(void* const* d_in, const int* in_sizes, int n_in,
                              void* d_out, int out_size, void* d_ws, size_t ws_size,
                              hipStream_t stream) {
    const float* x      = (const float*)d_in[0];
    const float* qkv_w  = (const float*)d_in[1];
    const float* proj_w = (const float*)d_in[2];
    const float* proj_b = (const float*)d_in[3];
    const float* alpha  = (const float*)d_in[4];
    const float* beta   = (const float*)d_in[5];
    const float* gamma  = (const float*)d_in[6];
    const float* ln1_w  = (const float*)d_in[7];
    const float* ln1_b  = (const float*)d_in[8];
    const float* ln2_w  = (const float*)d_in[9];
    const float* ln2_b  = (const float*)d_in[10];
    const float* w1     = (const float*)d_in[11];
    const float* b1     = (const float*)d_in[12];
    const float* w2     = (const float*)d_in[13];
    const float* b2     = (const float*)d_in[14];
    float* out = (float*)d_out;           // fp32 output; also doubles as x1 buffer

    // ws layout unchanged (see journal)
    char* base = (char*)d_ws;
    bf16* wq_bf = (bf16*)base;                 // 1152x384
    bf16* wp_bf = wq_bf + 442368;              // 384x384
    bf16* w1_bf = wq_bf + 589824;              // 1536x384
    bf16* w2_bf = wq_bf + 1179648;             // 384x1536
    bf16* h      = (bf16*)(base + 3538944);
    bf16* qkv    = (bf16*)(base + 9830400);
    bf16* attn_o = (bf16*)(base + 28704768);
    bf16* m      = qkv;                        // overlays qkv+attn_o (both dead by mlp1)
    bf16* Pp     = (bf16*)(base + 34996224);   // 2*TC (proj split-K partials)
    bf16* Pm     = (bf16*)(base + 34996224);   // 4*TC (mlp2 split-K partials; Pp dead)

    prep_kernel<<<1728 + T_TOK/4, 256, 0, stream>>>(
        qkv_w, proj_w, w1, w2, wq_bf, x, ln1_w, ln1_b, h);
    gemm_bt<EPI_QKV, 384, 1, bf16><<<dim3(9, 64, 1), 256, 0, stream>>>(
        h, wq_bf, nullptr, qkv, T_TOK, 1152);
    attn_kernel<<<768, 256, 0, stream>>>(
        qkv, qkv + TC, qkv + 2*TC, alpha, beta, gamma, attn_o);
    gemm_bt<EPI_NONE, 384, 2, bf16><<<dim3(3, 64, 2), 256, 0, stream>>>(
        attn_o, wp_bf, nullptr, Pp, T_TOK, DIMC);
    ln2_fused<<<T_TOK/4, 256, 0, stream>>>(x, Pp, Pp + TC, proj_b, ln2_w, ln2_b, out, h);
    gemm_bt<EPI_GELU, 384, 1, bf16><<<dim3(12, 64, 1), 256, 0, stream>>>(
        h, w1_bf, b1, m, T_TOK, MLPD);
    gemm_bt<EPI_NONE, 1536, 4, bf16><<<dim3(3, 64, 4), 256, 0, stream>>>(
        m, w2_bf, nullptr, Pm, T_TOK, DIMC);
    reduce4<<<TC/4/256, 256, 0, stream>>>(out, Pm, Pm + TC, Pm + 2*TC, Pm + 3*TC, b2);
}